// Round 20
// baseline (654.932 us; speedup 1.0000x reference)
//
#include <hip/hip_runtime.h>
#include <hip/hip_fp16.h>
#include <hip/hip_bf16.h>
#include <math.h>

#define HEADS  32
#define SEQ_Q  512
#define SEQ_KV 4096
#define D      128
#define TBQ    16     // q_extend tokens per block
#define TBK    32     // prep tokens per block
#define HS     (HEADS * SEQ_Q)
#define KVSPL  4
#define KVLEN  (SEQ_KV / KVSPL)

typedef __attribute__((ext_vector_type(8))) short short8v;
typedef __attribute__((ext_vector_type(4))) float f32x4;

#define DROT 0.0045f                       // > 2^-8 hard C-S bound for unit·unit
#define DCSG 0.005f                        // > 2^-8, sign-inner C-S coefficient
#define CORR (1.25331413731550025f / 128.0f)  // sqrt(pi/2)/qjl_dim
#define LCW1 128   // per-wave bucketize-risky list cap
#define LCW2 256   // per-wave sign-risky list cap

__device__ __forceinline__ float f16r(float x) {
    return __half2float(__float2half(x));
}
__device__ __forceinline__ ushort f2bf(float x) {
    __hip_bfloat16 b = __float2bfloat16(x);
    return __builtin_bit_cast(ushort, b);
}

// ---------------------------------------------------------------------------
// init: bf16 packs of R, Rv, qjl
// ---------------------------------------------------------------------------
__global__ __launch_bounds__(256) void pack3(
    const float* __restrict__ Rf, const float* __restrict__ Rvf,
    const float* __restrict__ qjlf,
    ushort* __restrict__ Rb, ushort* __restrict__ Rvb, ushort* __restrict__ qjlb)
{
    int idx = blockIdx.x * 256 + threadIdx.x;
    if (idx < 16384) Rb[idx] = f2bf(Rf[idx]);
    else if (idx < 32768) Rvb[idx - 16384] = f2bf(Rvf[idx - 16384]);
    else if (idx < 49152) qjlb[idx - 32768] = f2bf(qjlf[idx - 32768]);
}

// ---------------------------------------------------------------------------
// init: MT[i][j] = (R @ qjl^T)[j][i]; row norms of qjl, MT
// ---------------------------------------------------------------------------
__global__ __launch_bounds__(128) void minit(
    const float* __restrict__ Rf, const float* __restrict__ qjlf,
    float* __restrict__ MTf, ushort* __restrict__ MTb,
    float* __restrict__ qn, float* __restrict__ mn)
{
    const int i = blockIdx.x, j = threadIdx.x;
    const float* rr = Rf + (size_t)j * D;
    const float* qr = qjlf + (size_t)i * D;
    float acc = 0.f;
    #pragma unroll 4
    for (int d = 0; d < D; d += 4) {
        float4 r4 = *reinterpret_cast<const float4*>(rr + d);
        float4 q4 = *reinterpret_cast<const float4*>(qr + d);
        acc += r4.x * q4.x + r4.y * q4.y + r4.z * q4.z + r4.w * q4.w;
    }
    MTf[(size_t)i * D + j] = acc;
    MTb[(size_t)i * D + j] = f2bf(acc);

    __shared__ float r1[2], r2[2];
    float s1 = acc * acc;
    float qv = qr[j];
    float s2 = qv * qv;
    #pragma unroll
    for (int o = 32; o > 0; o >>= 1) {
        s1 += __shfl_xor(s1, o, 64);
        s2 += __shfl_xor(s2, o, 64);
    }
    if ((j & 63) == 0) { r1[j >> 6] = s1; r2[j >> 6] = s2; }
    __syncthreads();
    if (j == 0) { mn[i] = sqrtf(r1[0] + r1[1]); qn[i] = sqrtf(r2[0] + r2[1]); }
}

// ---------------------------------------------------------------------------
// Key compression. TBK=32, 4 waves; wave w owns output cols [32w, 32w+32).
// waves_per_eu(5,8) probe: allocator budget 512/5=102 >= 64-reg live set
// (should pick 64, no spill) while scheduler min-target rises to 5/EU.
// ---------------------------------------------------------------------------
__global__ __attribute__((amdgpu_flat_work_group_size(256, 256)))
__attribute__((amdgpu_waves_per_eu(5, 8))) void key_compress(
    const float* __restrict__ k, const float* __restrict__ Rf,
    const float* __restrict__ qjlf, const float* __restrict__ kcg,
    const float* __restrict__ kbg,
    const ushort* __restrict__ Rb, const ushort* __restrict__ qjlb,
    const ushort* __restrict__ MTb, const float* __restrict__ MTf,
    const float* __restrict__ qnA, const float* __restrict__ mnA,
    ushort* __restrict__ Kx)
{
    __shared__ __align__(16) ushort u_lds[TBK][136];   // P0-P1: unit vecs; P5+: sign staging
    __shared__ ushort cb_lds[TBK][136];
    __shared__ unsigned char idx_lds[TBK][128];
    __shared__ float swork[4][TBK];
    __shared__ float cwork[4][TBK];
    __shared__ float sumsq[TBK], nrmA[TBK], invA[TBK], hnA[TBK], rnA[TBK],
                     sA[TBK], cbnA[TBK];
    __shared__ float kcl[8], kbl[7];
    __shared__ ushort list1[4][LCW1];
    __shared__ ushort list2[4][LCW2];

    const int tid = threadIdx.x;
    const int base = blockIdx.x * TBK;
    const int w = tid >> 6, l = tid & 63, lr = l & 15, lh = l >> 4;

    if (tid < 8) kcl[tid] = kcg[tid];
    if (tid < 7) kbl[tid] = kbg[tid];

    // ---- P0: load, per-token norms, u to LDS (bf16) ----
    const int j0 = tid & 127, th = tid >> 7;
    {
        float kv[16];
        #pragma unroll
        for (int tt = 0; tt < 16; ++tt)
            kv[tt] = k[(size_t)(base + th * 16 + tt) * D + j0];
        float ss[16];
        #pragma unroll
        for (int tt = 0; tt < 16; ++tt) ss[tt] = kv[tt] * kv[tt];
        #pragma unroll
        for (int o = 32; o > 0; o >>= 1) {
            #pragma unroll
            for (int tt = 0; tt < 16; ++tt) ss[tt] += __shfl_xor(ss[tt], o, 64);
        }
        if (l == 0) {
            #pragma unroll
            for (int tt = 0; tt < 16; ++tt) swork[w][tt] = ss[tt];
        }
        __syncthreads();
        if (tid < TBK) {
            int t = tid;
            float s2 = swork[(t >> 4) * 2][t & 15] + swork[(t >> 4) * 2 + 1][t & 15];
            sumsq[t] = s2;
            float n = sqrtf(s2);
            nrmA[t] = n;
            invA[t] = 1.0f / (n + 1e-8f);
            hnA[t] = f16r(n);
        }
        __syncthreads();
        #pragma unroll
        for (int tt = 0; tt < 16; ++tt) {
            int t = th * 16 + tt;
            u_lds[t][j0] = f2bf(kv[tt] * invA[t]);
        }
    }
    __syncthreads();

    // ---- P1: MFMA rot+kq; bucketize (2-boundary dmin); risky list ----
    f32x4 kq[2][2];          // [n][a] — 16 VGPR, persists to P5
    float sloc[8], cloc[8];
    #pragma unroll
    for (int i = 0; i < 8; ++i) { sloc[i] = 0.f; cloc[i] = 0.f; }
    int c1 = 0;
    const float b0 = kbl[0], b1 = kbl[1], b2 = kbl[2], b3 = kbl[3],
                b4 = kbl[4], b5 = kbl[5], b6 = kbl[6];

    #pragma unroll
    for (int n = 0; n < 2; ++n) {
        short8v bR[4], bQ[4];
        #pragma unroll
        for (int kk = 0; kk < 4; ++kk) {
            size_t off = (size_t)(32 * w + 16 * n + lr) * D + kk * 32 + lh * 8;
            bR[kk] = *reinterpret_cast<const short8v*>(Rb + off);
            bQ[kk] = *reinterpret_cast<const short8v*>(qjlb + off);
        }
        #pragma unroll
        for (int a = 0; a < 2; ++a) {
            int tr = 16 * a + lr;
            short8v av[4];
            #pragma unroll
            for (int kk = 0; kk < 4; ++kk)
                av[kk] = *reinterpret_cast<const short8v*>(&u_lds[tr][kk * 32 + lh * 8]);
            f32x4 rt = (f32x4)(0.f), kqa = (f32x4)(0.f);
            #pragma unroll
            for (int kk = 0; kk < 4; ++kk)
                rt = __builtin_amdgcn_mfma_f32_16x16x32_bf16(av[kk], bR[kk], rt, 0, 0, 0);
            #pragma unroll
            for (int kk = 0; kk < 4; ++kk)
                kqa = __builtin_amdgcn_mfma_f32_16x16x32_bf16(av[kk], bQ[kk], kqa, 0, 0, 0);
            kq[n][a] = kqa;

            #pragma unroll
            for (int r = 0; r < 4; ++r) {
                float x = rt[r];
                int idx = (x > b0) + (x > b1) + (x > b2) + (x > b3) +
                          (x > b4) + (x > b5) + (x > b6);
                float cv = kcl[idx];
                int t = 16 * a + 4 * lh + r;
                int jj = 32 * w + 16 * n + lr;
                idx_lds[t][jj] = (unsigned char)idx;
                cb_lds[t][jj] = f2bf(cv);
                sloc[a * 4 + r] += cv * x;
                cloc[a * 4 + r] += cv * cv;
                // nearest boundary is adjacent to the bucket (exact)
                float blo = kbl[(idx > 0) ? idx - 1 : 0];
                float bhi = kbl[(idx < 7) ? idx : 6];
                float dmin = fminf(fabsf(x - blo), fabsf(x - bhi));
                bool risky = dmin < DROT;
                unsigned long long m = __ballot(risky);
                if (risky) {
                    int pos = c1 + __popcll(m & ((1ULL << l) - 1ULL));
                    if (pos < LCW1) list1[w][pos] = (ushort)((t << 7) | jj);
                }
                c1 += (int)__popcll(m);
            }
        }
    }
    // per-wave partial s / |cb|^2 sums -> LDS
    #pragma unroll
    for (int a = 0; a < 2; ++a) {
        #pragma unroll
        for (int r = 0; r < 4; ++r) {
            float s = sloc[a * 4 + r], c = cloc[a * 4 + r];
            #pragma unroll
            for (int o = 1; o < 16; o <<= 1) {
                s += __shfl_xor(s, o, 64);
                c += __shfl_xor(c, o, 64);
            }
            if (lr == 0) {
                int t = 16 * a + 4 * lh + r;
                swork[w][t] = s;
                cwork[w][t] = c;
            }
        }
    }
    __syncthreads();   // u_lds fully read by all waves; safe to reuse after here

    if (tid < TBK) {
        int t = tid;
        sA[t] = swork[0][t] + swork[1][t] + swork[2][t] + swork[3][t];
        cbnA[t] = cwork[0][t] + cwork[1][t] + cwork[2][t] + cwork[3][t];
    }
    __syncthreads();

    // ---- FB1: wave-cooperative coalesced exact f32 recompute ----
    {
        int n1 = min(c1, LCW1);
        const int g = l >> 4, li = l & 15;
        for (int e0 = 0; e0 < n1; e0 += 4) {
            int ee = e0 + g;
            bool act = ee < n1;
            int ent = act ? list1[w][ee] : list1[w][0];
            int t = ent >> 7, jj = ent & 127;
            const float* kr = k + (size_t)(base + t) * D + 8 * li;
            const float* rr = Rf + (size_t)jj * D + 8 * li;
            float4 ka = *reinterpret_cast<const float4*>(kr);
            float4 kb4 = *reinterpret_cast<const float4*>(kr + 4);
            float4 ra = *reinterpret_cast<const float4*>(rr);
            float4 rb4 = *reinterpret_cast<const float4*>(rr + 4);
            float iv = invA[t];
            float part = (ka.x * iv) * ra.x + (ka.y * iv) * ra.y +
                         (ka.z * iv) * ra.z + (ka.w * iv) * ra.w +
                         (kb4.x * iv) * rb4.x + (kb4.y * iv) * rb4.y +
                         (kb4.z * iv) * rb4.z + (kb4.w * iv) * rb4.w;
            #pragma unroll
            for (int o = 1; o < 16; o <<= 1) part += __shfl_xor(part, o, 64);
            if (act && li == 0) {
                float acc = part;
                int ni = (acc > kbl[0]) + (acc > kbl[1]) + (acc > kbl[2]) + (acc > kbl[3]) +
                         (acc > kbl[4]) + (acc > kbl[5]) + (acc > kbl[6]);
                int oi = idx_lds[t][jj];
                if (ni != oi) {
                    float co = kcl[oi], cn = kcl[ni];
                    idx_lds[t][jj] = (unsigned char)ni;
                    cb_lds[t][jj] = f2bf(cn);
                    atomicAdd(&sA[t], (cn - co) * acc);
                    atomicAdd(&cbnA[t], cn * cn - co * co);
                }
            }
        }
    }
    __syncthreads();

    // ---- P3: residual norm via identity ----
    if (tid < TBK) {
        int t = tid;
        float n = nrmA[t];
        float r2v = sumsq[t] - 2.f * n * (n + 1e-8f) * sA[t] + n * n * cbnA[t];
        rnA[t] = f16r(sqrtf(fmaxf(r2v, 0.f)));
    }
    __syncthreads();

    // ---- P4+P5: in2 MFMA consumed immediately; signs -> u_lds (overlay) ----
    float nT8[8], rnT8[8], cbL8[8];
    #pragma unroll
    for (int a = 0; a < 2; ++a) {
        #pragma unroll
        for (int r = 0; r < 4; ++r) {
            int t = 16 * a + 4 * lh + r;
            nT8[a * 4 + r] = nrmA[t];
            rnT8[a * 4 + r] = rnA[t];
            cbL8[a * 4 + r] = sqrtf(cbnA[t]);
        }
    }
    int c2 = 0;
    #pragma unroll
    for (int n = 0; n < 2; ++n) {
        short8v bM[4];
        #pragma unroll
        for (int kk = 0; kk < 4; ++kk)
            bM[kk] = *reinterpret_cast<const short8v*>(
                MTb + (size_t)(32 * w + 16 * n + lr) * D + kk * 32 + lh * 8);
        float qn2 = qnA[32 * w + 16 * n + lr];
        float mn2 = mnA[32 * w + 16 * n + lr];
        #pragma unroll
        for (int a = 0; a < 2; ++a) {
            int tr = 16 * a + lr;
            short8v ac[4];
            #pragma unroll
            for (int kk = 0; kk < 4; ++kk)
                ac[kk] = *reinterpret_cast<const short8v*>(&cb_lds[tr][kk * 32 + lh * 8]);
            f32x4 in2a = (f32x4)(0.f);
            #pragma unroll
            for (int kk = 0; kk < 4; ++kk)
                in2a = __builtin_amdgcn_mfma_f32_16x16x32_bf16(ac[kk], bM[kk], in2a, 0, 0, 0);

            #pragma unroll
            for (int r = 0; r < 4; ++r) {
                int t = 16 * a + 4 * lh + r;
                float nT = nT8[a * 4 + r], rnT = rnT8[a * 4 + r], cbL = cbL8[a * 4 + r];
                int i = 32 * w + 16 * n + lr;
                float inr = (nT + 1e-8f) * kq[n][a][r] - nT * in2a[r];
                float dl = DCSG * ((nT + 1e-8f) * qn2 + nT * cbL * mn2);
                bool risky = fabsf(inr) < dl;
                unsigned long long m = __ballot(risky);
                if (risky) {
                    int pos = c2 + __popcll(m & ((1ULL << l) - 1ULL));
                    if (pos < LCW2) list2[w][pos] = (ushort)((t << 7) | i);
                }
                c2 += (int)__popcll(m);
                float sg = (inr >= 0.f) ? 1.f : -1.f;
                u_lds[t][i] = f2bf(sg * rnT * CORR);
            }
        }
    }
    // (no barrier: FB2 touches only this wave's list/columns)

    // ---- FB2: wave-cooperative exact sign recompute -> u_lds (overlay) ----
    {
        int n2 = min(c2, LCW2);
        const int g = l >> 4, li = l & 15;
        for (int e0 = 0; e0 < n2; e0 += 4) {
            int ee = e0 + g;
            bool act = ee < n2;
            int ent = act ? list2[w][ee] : list2[w][0];
            int t = ent >> 7, i = ent & 127;
            const float* kr = k + (size_t)(base + t) * D + 8 * li;
            const float* qr = qjlf + (size_t)i * D + 8 * li;
            const float* mr = MTf + (size_t)i * D + 8 * li;
            float4 k0 = *reinterpret_cast<const float4*>(kr);
            float4 k1 = *reinterpret_cast<const float4*>(kr + 4);
            float4 q0 = *reinterpret_cast<const float4*>(qr);
            float4 q1 = *reinterpret_cast<const float4*>(qr + 4);
            float4 m0 = *reinterpret_cast<const float4*>(mr);
            float4 m1 = *reinterpret_cast<const float4*>(mr + 4);
            uchar4 i0 = *reinterpret_cast<const uchar4*>(&idx_lds[t][8 * li]);
            uchar4 i1 = *reinterpret_cast<const uchar4*>(&idx_lds[t][8 * li + 4]);
            float p1 = k0.x * q0.x + k0.y * q0.y + k0.z * q0.z + k0.w * q0.w +
                       k1.x * q1.x + k1.y * q1.y + k1.z * q1.z + k1.w * q1.w;
            float p2 = kcl[i0.x] * m0.x + kcl[i0.y] * m0.y +
                       kcl[i0.z] * m0.z + kcl[i0.w] * m0.w +
                       kcl[i1.x] * m1.x + kcl[i1.y] * m1.y +
                       kcl[i1.z] * m1.z + kcl[i1.w] * m1.w;
            #pragma unroll
            for (int o = 1; o < 16; o <<= 1) {
                p1 += __shfl_xor(p1, o, 64);
                p2 += __shfl_xor(p2, o, 64);
            }
            if (act && li == 0) {
                float inr = p1 - nrmA[t] * p2;
                float sg = (inr >= 0.f) ? 1.f : -1.f;
                u_lds[t][i] = f2bf(sg * rnA[t] * CORR);
            }
        }
    }
    __syncthreads();

    // ---- P6: unified coalesced write of full 512B Kx rows ----
    {
        const int t = tid >> 3, p = tid & 7;
        ushort* dst = Kx + (size_t)(base + t) * 256;
        float hn = hnA[t];
        #pragma unroll
        for (int i = 0; i < 2; ++i) {
            int c0 = 16 * p + 8 * i;
            uchar4 ia = *reinterpret_cast<const uchar4*>(&idx_lds[t][c0]);
            uchar4 ib = *reinterpret_cast<const uchar4*>(&idx_lds[t][c0 + 4]);
            uint pk0 = (uint)f2bf(kcl[ia.x] * hn) | ((uint)f2bf(kcl[ia.y] * hn) << 16);
            uint pk1 = (uint)f2bf(kcl[ia.z] * hn) | ((uint)f2bf(kcl[ia.w] * hn) << 16);
            uint pk2 = (uint)f2bf(kcl[ib.x] * hn) | ((uint)f2bf(kcl[ib.y] * hn) << 16);
            uint pk3 = (uint)f2bf(kcl[ib.z] * hn) | ((uint)f2bf(kcl[ib.w] * hn) << 16);
            *reinterpret_cast<uint4*>(dst + c0) = make_uint4(pk0, pk1, pk2, pk3);
            uint4 sv = *reinterpret_cast<const uint4*>(&u_lds[t][c0]);
            *reinterpret_cast<uint4*>(dst + 128 + c0) = sv;
        }
    }
}

// ---------------------------------------------------------------------------
// Value compression. TBK=32:  VT[h][d][tok] = bf16(vc[idx] * f16(vn))
// ---------------------------------------------------------------------------
__global__ __attribute__((amdgpu_flat_work_group_size(256, 256)))
__attribute__((amdgpu_waves_per_eu(5, 8))) void value_compress(
    const float* __restrict__ v, const float* __restrict__ Rvf,
    const float* __restrict__ vcg, const float* __restrict__ vbg,
    const ushort* __restrict__ Rvb, ushort* __restrict__ VT)
{
    __shared__ ushort u_lds[TBK][136];
    __shared__ unsigned char idx_lds[TBK][128];
    __shared__ float red[4][TBK];
    __shared__ float nrmA[TBK], invA[TBK], hnA[TBK];
    __shared__ float vcl[16], vbl[15];
    __shared__ ushort list1[4][LCW1];

    const int tid = threadIdx.x;
    const int base = blockIdx.x * TBK;
    const int w = tid >> 6, l = tid & 63, lr = l & 15, lh = l >> 4;

    if (tid < 16) vcl[tid] = vcg[tid];
    if (tid < 15) vbl[tid] = vbg[tid];

    const int j0 = tid & 127, th = tid >> 7;
    {
        float kv[16];
        #pragma unroll
        for (int tt = 0; tt < 16; ++tt)
            kv[tt] = v[(size_t)(base + th * 16 + tt) * D + j0];
        float ss[16];
        #pragma unroll
        for (int tt = 0; tt < 16; ++tt) ss[tt] = kv[tt] * kv[tt];
        #pragma unroll
        for (int o = 32; o > 0; o >>= 1) {
            #pragma unroll
            for (int tt = 0; tt < 16; ++tt) ss[tt] += __shfl_xor(ss[tt], o, 64);
        }
        if (l == 0) {
            #pragma unroll
            for (int tt = 0; tt < 16; ++tt) red[w][tt] = ss[tt];
        }
        __syncthreads();
        if (tid < TBK) {
            int t = tid;
            float s2 = red[(t >> 4) * 2][t & 15] + red[(t >> 4) * 2 + 1][t & 15];
            float n = sqrtf(s2);
            nrmA[t] = n;
            invA[t] = 1.0f / (n + 1e-8f);
            hnA[t] = f16r(n);
        }
        __syncthreads();
        #pragma unroll
        for (int tt = 0; tt < 16; ++tt) {
            int t = th * 16 + tt;
            u_lds[t][j0] = f2bf(kv[tt] * invA[t]);
        }
    }
    __syncthreads();

    int c1 = 0;
    float vbr[15];
    #pragma unroll
    for (int i = 0; i < 15; ++i) vbr[i] = vbl[i];

    #pragma unroll
    for (int n = 0; n < 2; ++n) {
        short8v bV[4];
        #pragma unroll
        for (int kk = 0; kk < 4; ++kk)
            bV[kk] = *reinterpret_cast<const short8v*>(
                Rvb + (size_t)(32 * w + 16 * n + lr) * D + kk * 32 + lh * 8);
        #pragma unroll
        for (int a = 0; a < 2; ++a) {
            int tr = 16 * a + lr;
            short8v av[4];
            #pragma unroll
            for (int kk = 0; kk < 4; ++kk)
                av[kk] = *reinterpret_cast<const short8v*>(&u_lds[tr][kk * 32 + lh * 8]);
            f32x4 rt = (f32x4)(0.f);
            #pragma unroll
            for (int kk = 0; kk < 4; ++kk)
                rt = __builtin_amdgcn_mfma_f32_16x16x32_bf16(av[kk], bV[kk], rt, 0, 0, 0);

            #pragma unroll
            for (int r = 0; r < 4; ++r) {
                float x = rt[r];
                int idx = 0;
                #pragma unroll
                for (int i = 0; i < 15; ++i) idx += (x > vbr[i]);
                int t = 16 * a + 4 * lh + r;
                int jj = 32 * w + 16 * n + lr;
                idx_lds[t][jj] = (unsigned char)idx;
                // nearest boundary is adjacent to the bucket (exact)
                float blo = vbl[(idx > 0) ? idx - 1 : 0];
                float bhi = vbl[(idx < 15) ? idx : 14];
                float dmin = fminf(fabsf(x - blo), fabsf(x - bhi));
                bool risky = dmin < DROT;
                unsigned long long m = __ballot(risky);
                if (risky) {
                    int pos = c1 + __popcll(m & ((1ULL << l) - 1ULL));
                    if (pos < LCW1) list1[w][pos] = (ushort)((t << 7) | jj);
                }
                c1 += (int)__popcll(m);
            }
        }
    }
    __syncthreads();

    // ---- FB: wave-cooperative coalesced exact recompute ----
    {
        int n1 = min(c1, LCW1);
        const int g = l >> 4, li = l & 15;
        for (int e0 = 0; e0 < n1; e0 += 4) {
            int ee = e0 + g;
            bool act = ee < n1;
            int ent = act ? list1[w][ee] : list1[w][0];
            int t = ent >> 7, jj = ent & 127;
            const float* kr = v + (size_t)(base + t) * D + 8 * li;
            const float* rr = Rvf + (size_t)jj * D + 8 * li;
            float4 ka = *reinterpret_cast<const float4*>(kr);
            float4 kb4 = *reinterpret_cast<const float4*>(kr + 4);
            float4 ra = *reinterpret_cast<const float4*>(rr);
            float4 rb4 = *reinterpret_cast<const float4*>(rr + 4);
            float iv = invA[t];
            float part = (ka.x * iv) * ra.x + (ka.y * iv) * ra.y +
                         (ka.z * iv) * ra.z + (ka.w * iv) * ra.w +
                         (kb4.x * iv) * rb4.x + (kb4.y * iv) * rb4.y +
                         (kb4.z * iv) * rb4.z + (kb4.w * iv) * rb4.w;
            #pragma unroll
            for (int o = 1; o < 16; o <<= 1) part += __shfl_xor(part, o, 64);
            if (act && li == 0) {
                int ni = 0;
                #pragma unroll
                for (int i = 0; i < 15; ++i) ni += (part > vbl[i]);
                idx_lds[t][jj] = (unsigned char)ni;
            }
        }
    }
    __syncthreads();

    // ---- transposed coalesced write ----
    {
        const int c = tid & 127, g = tid >> 7;
        const int hh = base >> 12;
        const int tk = base & 4095;
        ushort tmp[16];
        #pragma unroll
        for (int tt = 0; tt < 16; ++tt) {
            int t = 16 * g + tt;
            tmp[tt] = f2bf(vcl[idx_lds[t][c]] * hnA[t]);
        }
        ushort* dst = VT + ((size_t)hh * D + c) * SEQ_KV + tk + 16 * g;
        uint pk[8];
        #pragma unroll
        for (int i = 0; i < 8; ++i)
            pk[i] = (uint)tmp[2 * i] | ((uint)tmp[2 * i + 1] << 16);
        *reinterpret_cast<uint4*>(dst)     = make_uint4(pk[0], pk[1], pk[2], pk[3]);
        *reinterpret_cast<uint4*>(dst + 8) = make_uint4(pk[4], pk[5], pk[6], pk[7]);
    }
}

// ---------------------------------------------------------------------------
// Q extension: Qx[0:128] = bf16(q@R^T), Qx[128:256] = bf16(q@qjl^T)
// ---------------------------------------------------------------------------
__global__ __launch_bounds__(128) void q_extend(
    const float* __restrict__ q, const float* __restrict__ Rf,
    const float* __restrict__ qjlf, ushort* __restrict__ Qxo)
{
    __shared__ float u[TBQ][132];
    const int j = threadIdx.x;
    const int base = blockIdx.x * TBQ;

    #pragma unroll
    for (int t = 0; t < TBQ; ++t)
        u[t][j] = q[(size_t)(base + t) * D + j];
    __syncthreads();

    float accr[TBQ], accq[TBQ];
    #pragma unroll
    for (int t = 0; t < TBQ; ++t) { accr[t] = 0.f; accq[t] = 0.f; }
    const float* Rr = Rf + (size_t)j * D;
    const float* Qr = qjlf + (size_t)j * D;
    #pragma unroll 2
    for (int d = 0; d < D; d += 4) {
        float4 r4 = *reinterpret_cast<const float4*>(Rr + d);
        float4 q4 = *reinterpret_cast<const float4*>(Qr + d);
        #pragma unroll
        for (int t = 0; t < TBQ; ++t) {
            float4 u4 = *reinterpret_cast<const float4*>(&u[t][d]);
            accr[t] += u4.x * r4.x + u4.y * r4.y + u4.z * r4.z + u4.w * r4.w;
            accq[t] += u4.x * q4.x + u4.y * q4.y + u4.z * q4.z + u4.w * q4.w;
        }
    }
    #pragma unroll
    for (int t = 0; t < TBQ; ++t) {
        Qxo[(size_t)(base + t) * 256 + j]       = f2bf(accr[t]);
        Qxo[(size_t)(base + t) * 256 + 128 + j] = f2bf(accq[t]);
    }
}

// ---------------------------------------------------------------------------
// MFMA flash attention, QT=128 mega-block: 512 threads / 8 waves.
// De-spill design (r14-proven): load->LDS immediately, waves_per_eu(4,4).
// grid: (HEADS, SEQ_Q/128, KVSPL)
// ---------------------------------------------------------------------------
__global__ __attribute__((amdgpu_flat_work_group_size(512, 512)))
__attribute__((amdgpu_waves_per_eu(4, 4))) void attention(
    const ushort* __restrict__ Qx, const ushort* __restrict__ Kx,
    const ushort* __restrict__ VT, float* __restrict__ Opart,
    float* __restrict__ MLp)
{
    __shared__ __align__(16) unsigned char arena[33792 + 18432 + 19456];
    ushort (*Ks)[264] = (ushort (*)[264])arena;                    // 33792 B
    ushort (*Vs)[72]  = (ushort (*)[72])(arena + 33792);           // 18432 B
    ushort (*Ps)[76]  = (ushort (*)[76])(arena + 33792 + 18432);   // 19456 B (128 rows)
    float (*Of)[130]  = (float (*)[130])arena;                     // 66560 B overlay (epilogue)

    const int tid = threadIdx.x;
    const int h   = blockIdx.x;
    const int q0  = blockIdx.y * 128;
    const int sp  = blockIdx.z;
    const int kvb = sp * KVLEN;
    const int w   = tid >> 6;          // 0..7 waves, 16 q-rows each
    const int l   = tid & 63;
    const int lr  = l & 15;
    const int lh  = l >> 4;
    const float scale = 0.08838834764831845f;  // 1/sqrt(128)

    short8v qa[8];
    {
        const ushort* qrow = Qx + ((size_t)h * SEQ_Q + q0 + w * 16 + lr) * 256 + lh * 8;
        #pragma unroll
        for (int kk = 0; kk < 8; ++kk)
            qa[kk] = __builtin_bit_cast(short8v,
                *reinterpret_cast<const uint4*>(qrow + kk * 32));
    }

    const int krow = tid >> 5, kc16 = tid & 31;   // K: 16 rows per instr
    const int vrow = tid >> 3, vc8  = tid & 7;    // V: 64 rows per instr
    const ushort* Kg = Kx + (size_t)h * SEQ_KV * 256;
    const ushort* Vg = VT + (size_t)h * D * SEQ_KV;

    f32x4 oacc[8];
    #pragma unroll
    for (int dc = 0; dc < 8; ++dc) oacc[dc] = (f32x4)(0.f);
    float mrow[4], lsum[4];
    #pragma unroll
    for (int r = 0; r < 4; ++r) { mrow[r] = -INFINITY; lsum[r] = 0.f; }

    for (int k0 = kvb; k0 < kvb + KVLEN; k0 += 64) {
        __syncthreads();   // all waves done reading previous tile
        {
            // load->store immediately; tmp regs dead before compute phase
            uint4 kt0 = *reinterpret_cast<const uint4*>(
                Kg + (size_t)(k0 + krow) * 256 + kc16 * 8);
            uint4 kt1 = *reinterpret_cast<const uint4*>(
                Kg + (size_t)(k0 + krow + 16) * 256 + kc16 * 8);
            uint4 kt2 = *reinterpret_cast<const uint4*>(
                Kg + (size_t)(k0 + krow + 32) * 256 + kc16 * 8);
            uint4 kt3 = *reinterpret_cast<const uint4*>(
                Kg + (size_t)(k0 + krow + 48) * 256 + kc16 * 8);
            uint4 vt0 = *reinterpret_cast<const uint4*>(
                Vg + (size_t)vrow * SEQ_KV + k0 + vc8 * 8);
            uint4 vt1 = *reinterpret_cast<const uint4*>(
                Vg + (size_t)(vrow + 64) * SEQ_KV + k0 + vc8 * 8);
            *reinterpret_cast<uint4*>(&Ks[krow][kc16 * 8])      = kt0;
            *reinterpret_cast<uint4*>(&Ks[krow + 16][kc16 * 8]) = kt1;
            *reinterpret_cast<uint4*>(&Ks[krow + 32][kc16 * 8]) = kt2;
            *reinterpret_cast<uint4*>(&Ks[krow + 48][kc16 * 8]) = kt3;
            *reinterpret_cast<uint4*>(&Vs[vrow][vc8 * 8])       = vt0;
            *reinterpret_cast<uint4*>(&Vs[vrow + 64][vc8 * 8])  = vt1;
        }
        __syncthreads();

        f32x4 sacc[4];
        #pragma unroll
        for (int kc = 0; kc < 4; ++kc) sacc[kc] = (f32x4)(0.f);
        #pragma unroll
        for (int kk = 0; kk < 8; ++kk) {
            #pragma unroll
            for (int kc = 0; kc < 4; ++kc) {
                short8v b = *reinterpret_cast<const short8v*>(
                    &Ks[kc * 16 + lr][kk * 32 + lh * 8]);
                sacc[kc] = __builtin_amdgcn_mfma_f32_16x16x32_bf16(
                    qa[kk], b, sacc[kc], 0, 0, 0);
            }
        }

        #pragma unroll
        for (int r = 0; r < 4; ++r) {
            float mx = fmaxf(fmaxf(sacc[0][r], sacc[1][r]),
                             fmaxf(sacc[2][r], sacc[3][r]));
            #pragma unroll
            for (int off = 8; off > 0; off >>= 1)
                mx = fmaxf(mx, __shfl_xor(mx, off, 64));
            mx *= scale;
            float mn = fmaxf(mrow[r], mx);
            float alpha = __expf(mrow[r] - mn);
            float pv[4], ps = 0.f;
            #pragma unroll
            for (int kc = 0; kc < 4; ++kc) {
                float p = __expf(sacc[kc][r] * scale - mn);
                pv[kc] = p; ps += p;
            }
            #pragma unroll
            for (int off = 8; off > 0; off >>= 1)
                ps += __shfl_xor(ps, off, 64);
            lsum[r] = lsum[r] * alpha + ps;
            mrow[r] = mn;
            #pragma unroll
            for (int kc = 0; kc < 4; ++kc)
                Ps[w * 16 + lh * 4 + r][kc * 16 + lr] = f2bf(pv[kc]);
            #pragma unroll
            for (int dc = 0; dc < 8; ++dc)
                oacc[dc][r] *= alpha;
        }

        #pragma unroll
        for (int kc2 = 0; kc2 < 2; ++kc2) {
            short8v pa = *reinterpret_cast<const short8v*>(
                &Ps[w * 16 + lr][kc2 * 32 + lh * 8]);
            #pragma unroll
            for (int dc = 0; dc < 8; ++dc) {
                short8v b = *reinterpret_cast<const short8v*>(
                    &Vs[dc * 16 + lr][kc2 * 32 + lh * 8]);
                oacc[dc] = __builtin_amdgcn_mfma_f32_16x16x32_bf16(
                    pa, b, oacc[dc], 0, 0, 0);
            }
        }
    }

    // ---- epilogue: O' -> LDS overlay -> dense global stores ----
    __syncthreads();   // all waves done reading Ks/Vs/Ps
    #pragma unroll
    for (int r = 0; r < 4; ++r) {
        int row = w * 16 + lh * 4 + r;
        #pragma unroll
        for (int dc = 0; dc < 8; ++dc)
            Of[row][dc * 16 + lr] = oacc[dc][r];
        if (lr == 0) {
            int rowg = h * SEQ_Q + q0 + row;
            MLp[((size_t)sp * HS + rowg) * 2 + 0] = mrow[r];
            MLp[((size_t)sp * HS + rowg) * 2 + 1] = lsum[r];
        }
    }
    __syncthreads();
    {
        const int rg = tid >> 5, cl = tid & 31;   // 16 row-groups
        float* obase = Opart + ((size_t)sp * HS + (size_t)h * SEQ_Q + q0) * D;
        #pragma unroll
        for (int it = 0; it < 8; ++it) {
            int row = it * 16 + rg;
            float4 vv = *reinterpret_cast<const float4*>(&Of[row][cl * 4]);
            *reinterpret_cast<float4*>(obase + (size_t)row * D + cl * 4) = vv;
        }
    }
}

// ---------------------------------------------------------------------------
// Combine KVSPL partials + Rv rotation epilogue.
// grid: HS/64, 256 threads. Block handles 64 output rows.
// ---------------------------------------------------------------------------
__global__ __launch_bounds__(256) void combine(
    const float* __restrict__ Opart, const float* __restrict__ MLp,
    const float* __restrict__ Rvf, float* __restrict__ out)
{
    __shared__ float O2[64][133];
    __shared__ float ws_s[KVSPL][64];

    const int tid = threadIdx.x;
    const int rowbase = blockIdx.x * 64;

    if (tid < 64) {
        int row = rowbase + tid;
        float mv[KVSPL], lv[KVSPL];
        #pragma unroll
        for (int s = 0; s < KVSPL; ++s) {
            mv[s] = MLp[((size_t)s * HS + row) * 2 + 0];
            lv[s] = MLp[((size_t)s * HS + row) * 2 + 1];
        }
        float M = mv[0];
        #pragma unroll
        for (int s = 1; s < KVSPL; ++s) M = fmaxf(M, mv[s]);
        float wv[KVSPL], den = 0.f;
        #pragma unroll
        for (int s = 0; s < KVSPL; ++s) {
            wv[s] = __expf(mv[s] - M);
            den += wv[s] * lv[s];
        }
        float inv = 1.0f / den;
        #pragma unroll
        for (int s = 0; s < KVSPL; ++s) ws_s[s][tid] = wv[s] * inv;
    }
    __syncthreads();

    const int rr = tid >> 2, qq = tid & 3;
    {
        int row = rowbase + rr;
        float o[32];
        #pragma unroll
        for (int i = 0; i < 32; ++i) o[i] = 0.f;
        #pragma unroll
        for (int s = 0; s < KVSPL; ++s) {
            const float* pa = Opart + ((size_t)s * HS + row) * D + qq * 32;
            float wgt = ws_s[s][rr];
            #pragma unroll
            for (int c8 = 0; c8 < 8; ++c8) {
                float4 va = *reinterpret_cast<const float4*>(pa + c8 * 4);
                o[c8 * 4 + 0] = fmaf(va.x, wgt, o[c8 * 4 + 0]);
                o[c8 * 4 + 1] = fmaf(va.y, wgt, o[c8 * 4 + 1]);
                o[c8 * 4 + 2] = fmaf(va.z, wgt, o[c8 * 4 + 2]);
                o[c8 * 4 + 3] = fmaf(va.w, wgt, o[c8 * 4 + 3]);
            }
        }
        #pragma unroll
        for (int i = 0; i < 32; ++i) O2[rr][qq * 32 + i] = o[i];
    }
    __syncthreads();

    {
        float acc[32];
        #pragma unroll
        for (int i = 0; i < 32; ++i) acc[i] = 0.f;
        #pragma unroll 2
        for (int jv = 0; jv < 128; ++jv) {
            float o = O2[rr][jv];
            const float* rv = Rvf + (size_t)jv * D + qq * 32;
            #pragma unroll
            for (int c8 = 0; c8 < 8; ++c8) {
                float4 r4 = *reinterpret_cast<const float4*>(rv + c8 * 4);
                acc[c8 * 4 + 0] = fmaf(o, r4.x, acc[c8 * 4 + 0]);
                acc[c8 * 4 + 1] = fmaf(o, r4.y, acc[c8 * 4 + 1]);
                acc[c8 * 4 + 2] = fmaf(o, r4.z, acc[c8 * 4 + 2]);
                acc[c8 * 4 + 3] = fmaf(o, r4.w, acc[c8 * 4 + 3]);
            }
        }
        float* orow = out + (size_t)(rowbase + rr) * D + qq * 32;
        #pragma unroll
        for (int c8 = 0; c8 < 8; ++c8)
            *reinterpret_cast<float4*>(orow + c8 * 4) =
                make_float4(acc[c8 * 4], acc[c8 * 4 + 1], acc[c8 * 4 + 2], acc[c8 * 4 + 3]);
    }
}

extern "C" void kernel_launch(void* const* d_in, const int* in_sizes, int n_in,
                              void* d_out, int out_size, void* d_ws, size_t ws_size,
                              hipStream_t stream)
{
    const float* q    = (const float*)d_in[0];
    const float* k    = (const float*)d_in[1];
    const float* v    = (const float*)d_in[2];
    const float* Rf   = (const float*)d_in[3];
    const float* qjlf = (const float*)d_in[4];
    const float* kc   = (const float*)d_in[5];
    const float* kb   = (const float*)d_in[6];
    const float* Rvf  = (const float*)d_in[7];
    const float* vc   = (const float*)d_in[8];
    const float* vb   = (const float*)d_in[9];
    float* out = (float*)d_out;

    // ws layout (bf16 unless noted)
    ushort* Kx    = (ushort*)d_ws;                       // [H*SKV][256]
    ushort* VT    = Kx + (size_t)HEADS * SEQ_KV * 256;   // [H][128][SKV]
    ushort* Qx    = VT + (size_t)HEADS * D * SEQ_KV;     // [H*SQ][256]
    ushort* Rb    = Qx + (size_t)HEADS * SEQ_Q * 256;    // [128][128]
    ushort* Rvb   = Rb + 16384;
    ushort* qjlb  = Rvb + 16384;
    ushort* MTb   = qjlb + 16384;
    float*  MTf   = (float*)(MTb + 16384);               // [128][128] f32
    float*  qn    = MTf + 16384;                         // [128]
    float*  mn    = qn + 128;                            // [128]
    float*  Opart = mn + 128;                            // [KVSPL][HS][128] f32
    float*  MLp   = Opart + (size_t)KVSPL * HS * D;      // [KVSPL][HS][2] f32

    pack3<<<192, 256, 0, stream>>>(Rf, Rvf, qjlf, Rb, Rvb, qjlb);
    minit<<<128, 128, 0, stream>>>(Rf, qjlf, MTf, MTb, qn, mn);
    key_compress<<<HEADS * SEQ_KV / TBK, 256, 0, stream>>>(
        k, Rf, qjlf, kc, kb, Rb, qjlb, MTb, MTf, qn, mn, Kx);
    value_compress<<<HEADS * SEQ_KV / TBK, 256, 0, stream>>>(
        v, Rvf, vc, vb, Rvb, VT);
    q_extend<<<HEADS * SEQ_Q / TBQ, 128, 0, stream>>>(q, Rf, qjlf, Qx);
    attention<<<dim3(HEADS, SEQ_Q / 128, KVSPL), 512, 0, stream>>>(
        Qx, Kx, VT, Opart, MLp);
    combine<<<HS / 64, 256, 0, stream>>>(Opart, MLp, Rvf, out);
}

// Round 21
// 531.677 us; speedup vs baseline: 1.2318x; 1.2318x over previous
//
#include <hip/hip_runtime.h>
#include <hip/hip_fp16.h>
#include <hip/hip_bf16.h>
#include <math.h>

#define HEADS  32
#define SEQ_Q  512
#define SEQ_KV 4096
#define D      128
#define TBQ    16     // q_extend tokens per block
#define TBK    32     // prep tokens per block
#define HS     (HEADS * SEQ_Q)
#define KVSPL  4
#define KVLEN  (SEQ_KV / KVSPL)

typedef __attribute__((ext_vector_type(8))) short short8v;
typedef __attribute__((ext_vector_type(4))) float f32x4;

#define DROT 0.0045f                       // > 2^-8 hard C-S bound for unit·unit
#define DCSG 0.005f                        // > 2^-8, sign-inner C-S coefficient
#define CORR (1.25331413731550025f / 128.0f)  // sqrt(pi/2)/qjl_dim
#define LCW1 128   // per-wave bucketize-risky list cap
#define LCW2 256   // per-wave sign-risky list cap

__device__ __forceinline__ float f16r(float x) {
    return __half2float(__float2half(x));
}
__device__ __forceinline__ ushort f2bf(float x) {
    __hip_bfloat16 b = __float2bfloat16(x);
    return __builtin_bit_cast(ushort, b);
}

// ---------------------------------------------------------------------------
// init: bf16 packs of R, Rv, qjl
// ---------------------------------------------------------------------------
__global__ __launch_bounds__(256) void pack3(
    const float* __restrict__ Rf, const float* __restrict__ Rvf,
    const float* __restrict__ qjlf,
    ushort* __restrict__ Rb, ushort* __restrict__ Rvb, ushort* __restrict__ qjlb)
{
    int idx = blockIdx.x * 256 + threadIdx.x;
    if (idx < 16384) Rb[idx] = f2bf(Rf[idx]);
    else if (idx < 32768) Rvb[idx - 16384] = f2bf(Rvf[idx - 16384]);
    else if (idx < 49152) qjlb[idx - 32768] = f2bf(qjlf[idx - 32768]);
}

// ---------------------------------------------------------------------------
// init: MT[i][j] = (R @ qjl^T)[j][i]; row norms of qjl, MT
// ---------------------------------------------------------------------------
__global__ __launch_bounds__(128) void minit(
    const float* __restrict__ Rf, const float* __restrict__ qjlf,
    float* __restrict__ MTf, ushort* __restrict__ MTb,
    float* __restrict__ qn, float* __restrict__ mn)
{
    const int i = blockIdx.x, j = threadIdx.x;
    const float* rr = Rf + (size_t)j * D;
    const float* qr = qjlf + (size_t)i * D;
    float acc = 0.f;
    #pragma unroll 4
    for (int d = 0; d < D; d += 4) {
        float4 r4 = *reinterpret_cast<const float4*>(rr + d);
        float4 q4 = *reinterpret_cast<const float4*>(qr + d);
        acc += r4.x * q4.x + r4.y * q4.y + r4.z * q4.z + r4.w * q4.w;
    }
    MTf[(size_t)i * D + j] = acc;
    MTb[(size_t)i * D + j] = f2bf(acc);

    __shared__ float r1[2], r2[2];
    float s1 = acc * acc;
    float qv = qr[j];
    float s2 = qv * qv;
    #pragma unroll
    for (int o = 32; o > 0; o >>= 1) {
        s1 += __shfl_xor(s1, o, 64);
        s2 += __shfl_xor(s2, o, 64);
    }
    if ((j & 63) == 0) { r1[j >> 6] = s1; r2[j >> 6] = s2; }
    __syncthreads();
    if (j == 0) { mn[i] = sqrtf(r1[0] + r1[1]); qn[i] = sqrtf(r2[0] + r2[1]); }
}

// ---------------------------------------------------------------------------
// Key compression. TBK=32, 4 waves; wave w owns output cols [32w, 32w+32).
// Wave-cooperative coalesced fallbacks; LDS sign staging; coalesced row write.
// ---------------------------------------------------------------------------
__global__ __launch_bounds__(256, 4) void key_compress(
    const float* __restrict__ k, const float* __restrict__ Rf,
    const float* __restrict__ qjlf, const float* __restrict__ kcg,
    const float* __restrict__ kbg,
    const ushort* __restrict__ Rb, const ushort* __restrict__ qjlb,
    const ushort* __restrict__ MTb, const float* __restrict__ MTf,
    const float* __restrict__ qnA, const float* __restrict__ mnA,
    ushort* __restrict__ Kx)
{
    __shared__ ushort u_lds[TBK][136];
    __shared__ ushort cb_lds[TBK][136];
    __shared__ __align__(16) ushort sign_lds[TBK][136];
    __shared__ unsigned char idx_lds[TBK][128];
    __shared__ float swork[4][TBK];
    __shared__ float cwork[4][TBK];
    __shared__ float sumsq[TBK], nrmA[TBK], invA[TBK], hnA[TBK], rnA[TBK],
                     sA[TBK], cbnA[TBK];
    __shared__ float kcl[8], kbl[7];
    __shared__ ushort list1[4][LCW1];
    __shared__ ushort list2[4][LCW2];

    const int tid = threadIdx.x;
    const int base = blockIdx.x * TBK;
    const int w = tid >> 6, l = tid & 63, lr = l & 15, lh = l >> 4;

    if (tid < 8) kcl[tid] = kcg[tid];
    if (tid < 7) kbl[tid] = kbg[tid];

    // ---- P0: load, per-token norms, u to LDS (bf16) ----
    const int j0 = tid & 127, th = tid >> 7;
    {
        float kv[16];
        #pragma unroll
        for (int tt = 0; tt < 16; ++tt)
            kv[tt] = k[(size_t)(base + th * 16 + tt) * D + j0];
        float ss[16];
        #pragma unroll
        for (int tt = 0; tt < 16; ++tt) ss[tt] = kv[tt] * kv[tt];
        #pragma unroll
        for (int o = 32; o > 0; o >>= 1) {
            #pragma unroll
            for (int tt = 0; tt < 16; ++tt) ss[tt] += __shfl_xor(ss[tt], o, 64);
        }
        if (l == 0) {
            #pragma unroll
            for (int tt = 0; tt < 16; ++tt) swork[w][tt] = ss[tt];
        }
        __syncthreads();
        if (tid < TBK) {
            int t = tid;
            float s2 = swork[(t >> 4) * 2][t & 15] + swork[(t >> 4) * 2 + 1][t & 15];
            sumsq[t] = s2;
            float n = sqrtf(s2);
            nrmA[t] = n;
            invA[t] = 1.0f / (n + 1e-8f);
            hnA[t] = f16r(n);
        }
        __syncthreads();
        #pragma unroll
        for (int tt = 0; tt < 16; ++tt) {
            int t = th * 16 + tt;
            u_lds[t][j0] = f2bf(kv[tt] * invA[t]);
        }
    }
    __syncthreads();

    // ---- P1: MFMA rot+kq; bucketize; per-wave risky list; s/|cb|^2 partials ----
    f32x4 kq[2][2];          // [n][a] — 16 VGPR, persists to P5
    float sloc[8], cloc[8];
    #pragma unroll
    for (int i = 0; i < 8; ++i) { sloc[i] = 0.f; cloc[i] = 0.f; }
    int c1 = 0;
    const float b0 = kbl[0], b1 = kbl[1], b2 = kbl[2], b3 = kbl[3],
                b4 = kbl[4], b5 = kbl[5], b6 = kbl[6];

    #pragma unroll
    for (int n = 0; n < 2; ++n) {
        short8v bR[4], bQ[4];
        #pragma unroll
        for (int kk = 0; kk < 4; ++kk) {
            size_t off = (size_t)(32 * w + 16 * n + lr) * D + kk * 32 + lh * 8;
            bR[kk] = *reinterpret_cast<const short8v*>(Rb + off);
            bQ[kk] = *reinterpret_cast<const short8v*>(qjlb + off);
        }
        #pragma unroll
        for (int a = 0; a < 2; ++a) {
            int tr = 16 * a + lr;
            short8v av[4];
            #pragma unroll
            for (int kk = 0; kk < 4; ++kk)
                av[kk] = *reinterpret_cast<const short8v*>(&u_lds[tr][kk * 32 + lh * 8]);
            f32x4 rt = (f32x4)(0.f), kqa = (f32x4)(0.f);
            #pragma unroll
            for (int kk = 0; kk < 4; ++kk)
                rt = __builtin_amdgcn_mfma_f32_16x16x32_bf16(av[kk], bR[kk], rt, 0, 0, 0);
            #pragma unroll
            for (int kk = 0; kk < 4; ++kk)
                kqa = __builtin_amdgcn_mfma_f32_16x16x32_bf16(av[kk], bQ[kk], kqa, 0, 0, 0);
            kq[n][a] = kqa;

            #pragma unroll
            for (int r = 0; r < 4; ++r) {
                float x = rt[r];
                int idx = (x > b0) + (x > b1) + (x > b2) + (x > b3) +
                          (x > b4) + (x > b5) + (x > b6);
                float cv = kcl[idx];
                int t = 16 * a + 4 * lh + r;
                int jj = 32 * w + 16 * n + lr;
                idx_lds[t][jj] = (unsigned char)idx;
                cb_lds[t][jj] = f2bf(cv);
                sloc[a * 4 + r] += cv * x;
                cloc[a * 4 + r] += cv * cv;
                float dmin = fabsf(x - b0);
                dmin = fminf(dmin, fabsf(x - b1)); dmin = fminf(dmin, fabsf(x - b2));
                dmin = fminf(dmin, fabsf(x - b3)); dmin = fminf(dmin, fabsf(x - b4));
                dmin = fminf(dmin, fabsf(x - b5)); dmin = fminf(dmin, fabsf(x - b6));
                bool risky = dmin < DROT;
                unsigned long long m = __ballot(risky);
                if (risky) {
                    int pos = c1 + __popcll(m & ((1ULL << l) - 1ULL));
                    if (pos < LCW1) list1[w][pos] = (ushort)((t << 7) | jj);
                }
                c1 += (int)__popcll(m);
            }
        }
    }
    // per-wave partial s / |cb|^2 sums -> LDS
    #pragma unroll
    for (int a = 0; a < 2; ++a) {
        #pragma unroll
        for (int r = 0; r < 4; ++r) {
            float s = sloc[a * 4 + r], c = cloc[a * 4 + r];
            #pragma unroll
            for (int o = 1; o < 16; o <<= 1) {
                s += __shfl_xor(s, o, 64);
                c += __shfl_xor(c, o, 64);
            }
            if (lr == 0) {
                int t = 16 * a + 4 * lh + r;
                swork[w][t] = s;
                cwork[w][t] = c;
            }
        }
    }
    __syncthreads();

    if (tid < TBK) {
        int t = tid;
        sA[t] = swork[0][t] + swork[1][t] + swork[2][t] + swork[3][t];
        cbnA[t] = cwork[0][t] + cwork[1][t] + cwork[2][t] + cwork[3][t];
    }
    __syncthreads();

    // ---- FB1: wave-cooperative coalesced exact f32 recompute ----
    {
        int n1 = min(c1, LCW1);
        const int g = l >> 4, li = l & 15;
        for (int e0 = 0; e0 < n1; e0 += 4) {
            int ee = e0 + g;
            bool act = ee < n1;
            int ent = act ? list1[w][ee] : list1[w][0];
            int t = ent >> 7, jj = ent & 127;
            const float* kr = k + (size_t)(base + t) * D + 8 * li;
            const float* rr = Rf + (size_t)jj * D + 8 * li;
            float4 ka = *reinterpret_cast<const float4*>(kr);
            float4 kb4 = *reinterpret_cast<const float4*>(kr + 4);
            float4 ra = *reinterpret_cast<const float4*>(rr);
            float4 rb4 = *reinterpret_cast<const float4*>(rr + 4);
            float iv = invA[t];
            float part = (ka.x * iv) * ra.x + (ka.y * iv) * ra.y +
                         (ka.z * iv) * ra.z + (ka.w * iv) * ra.w +
                         (kb4.x * iv) * rb4.x + (kb4.y * iv) * rb4.y +
                         (kb4.z * iv) * rb4.z + (kb4.w * iv) * rb4.w;
            #pragma unroll
            for (int o = 1; o < 16; o <<= 1) part += __shfl_xor(part, o, 64);
            if (act && li == 0) {
                float acc = part;
                int ni = (acc > kbl[0]) + (acc > kbl[1]) + (acc > kbl[2]) + (acc > kbl[3]) +
                         (acc > kbl[4]) + (acc > kbl[5]) + (acc > kbl[6]);
                int oi = idx_lds[t][jj];
                if (ni != oi) {
                    float co = kcl[oi], cn = kcl[ni];
                    idx_lds[t][jj] = (unsigned char)ni;
                    cb_lds[t][jj] = f2bf(cn);
                    atomicAdd(&sA[t], (cn - co) * acc);
                    atomicAdd(&cbnA[t], cn * cn - co * co);
                }
            }
        }
    }
    __syncthreads();

    // ---- P3: residual norm via identity ----
    if (tid < TBK) {
        int t = tid;
        float n = nrmA[t];
        float r2v = sumsq[t] - 2.f * n * (n + 1e-8f) * sA[t] + n * n * cbnA[t];
        rnA[t] = f16r(sqrtf(fmaxf(r2v, 0.f)));
    }
    __syncthreads();

    // ---- P4+P5: in2 MFMA consumed immediately; signs -> sign_lds ----
    int c2 = 0;
    #pragma unroll
    for (int n = 0; n < 2; ++n) {
        short8v bM[4];
        #pragma unroll
        for (int kk = 0; kk < 4; ++kk)
            bM[kk] = *reinterpret_cast<const short8v*>(
                MTb + (size_t)(32 * w + 16 * n + lr) * D + kk * 32 + lh * 8);
        float qn2 = qnA[32 * w + 16 * n + lr];
        float mn2 = mnA[32 * w + 16 * n + lr];
        #pragma unroll
        for (int a = 0; a < 2; ++a) {
            int tr = 16 * a + lr;
            short8v ac[4];
            #pragma unroll
            for (int kk = 0; kk < 4; ++kk)
                ac[kk] = *reinterpret_cast<const short8v*>(&cb_lds[tr][kk * 32 + lh * 8]);
            f32x4 in2a = (f32x4)(0.f);
            #pragma unroll
            for (int kk = 0; kk < 4; ++kk)
                in2a = __builtin_amdgcn_mfma_f32_16x16x32_bf16(ac[kk], bM[kk], in2a, 0, 0, 0);

            #pragma unroll
            for (int r = 0; r < 4; ++r) {
                int t = 16 * a + 4 * lh + r;
                float nT = nrmA[t], rnT = rnA[t], cbL = sqrtf(cbnA[t]);
                int i = 32 * w + 16 * n + lr;
                float inr = (nT + 1e-8f) * kq[n][a][r] - nT * in2a[r];
                float dl = DCSG * ((nT + 1e-8f) * qn2 + nT * cbL * mn2);
                bool risky = fabsf(inr) < dl;
                unsigned long long m = __ballot(risky);
                if (risky) {
                    int pos = c2 + __popcll(m & ((1ULL << l) - 1ULL));
                    if (pos < LCW2) list2[w][pos] = (ushort)((t << 7) | i);
                }
                c2 += (int)__popcll(m);
                float sg = (inr >= 0.f) ? 1.f : -1.f;
                sign_lds[t][i] = f2bf(sg * rnT * CORR);
            }
        }
    }
    // (no barrier: FB2 touches only this wave's list/columns)

    // ---- FB2: wave-cooperative exact sign recompute -> sign_lds ----
    {
        int n2 = min(c2, LCW2);
        const int g = l >> 4, li = l & 15;
        for (int e0 = 0; e0 < n2; e0 += 4) {
            int ee = e0 + g;
            bool act = ee < n2;
            int ent = act ? list2[w][ee] : list2[w][0];
            int t = ent >> 7, i = ent & 127;
            const float* kr = k + (size_t)(base + t) * D + 8 * li;
            const float* qr = qjlf + (size_t)i * D + 8 * li;
            const float* mr = MTf + (size_t)i * D + 8 * li;
            float4 k0 = *reinterpret_cast<const float4*>(kr);
            float4 k1 = *reinterpret_cast<const float4*>(kr + 4);
            float4 q0 = *reinterpret_cast<const float4*>(qr);
            float4 q1 = *reinterpret_cast<const float4*>(qr + 4);
            float4 m0 = *reinterpret_cast<const float4*>(mr);
            float4 m1 = *reinterpret_cast<const float4*>(mr + 4);
            uchar4 i0 = *reinterpret_cast<const uchar4*>(&idx_lds[t][8 * li]);
            uchar4 i1 = *reinterpret_cast<const uchar4*>(&idx_lds[t][8 * li + 4]);
            float p1 = k0.x * q0.x + k0.y * q0.y + k0.z * q0.z + k0.w * q0.w +
                       k1.x * q1.x + k1.y * q1.y + k1.z * q1.z + k1.w * q1.w;
            float p2 = kcl[i0.x] * m0.x + kcl[i0.y] * m0.y +
                       kcl[i0.z] * m0.z + kcl[i0.w] * m0.w +
                       kcl[i1.x] * m1.x + kcl[i1.y] * m1.y +
                       kcl[i1.z] * m1.z + kcl[i1.w] * m1.w;
            #pragma unroll
            for (int o = 1; o < 16; o <<= 1) {
                p1 += __shfl_xor(p1, o, 64);
                p2 += __shfl_xor(p2, o, 64);
            }
            if (act && li == 0) {
                float inr = p1 - nrmA[t] * p2;
                float sg = (inr >= 0.f) ? 1.f : -1.f;
                sign_lds[t][i] = f2bf(sg * rnA[t] * CORR);
            }
        }
    }
    __syncthreads();

    // ---- P6: unified coalesced write of full 512B Kx rows ----
    {
        const int t = tid >> 3, p = tid & 7;
        ushort* dst = Kx + (size_t)(base + t) * 256;
        float hn = hnA[t];
        #pragma unroll
        for (int i = 0; i < 2; ++i) {
            int c0 = 16 * p + 8 * i;
            uchar4 ia = *reinterpret_cast<const uchar4*>(&idx_lds[t][c0]);
            uchar4 ib = *reinterpret_cast<const uchar4*>(&idx_lds[t][c0 + 4]);
            uint pk0 = (uint)f2bf(kcl[ia.x] * hn) | ((uint)f2bf(kcl[ia.y] * hn) << 16);
            uint pk1 = (uint)f2bf(kcl[ia.z] * hn) | ((uint)f2bf(kcl[ia.w] * hn) << 16);
            uint pk2 = (uint)f2bf(kcl[ib.x] * hn) | ((uint)f2bf(kcl[ib.y] * hn) << 16);
            uint pk3 = (uint)f2bf(kcl[ib.z] * hn) | ((uint)f2bf(kcl[ib.w] * hn) << 16);
            *reinterpret_cast<uint4*>(dst + c0) = make_uint4(pk0, pk1, pk2, pk3);
            uint4 sv = *reinterpret_cast<const uint4*>(&sign_lds[t][c0]);
            *reinterpret_cast<uint4*>(dst + 128 + c0) = sv;
        }
    }
}

// ---------------------------------------------------------------------------
// Value compression. TBK=32:  VT[h][d][tok] = bf16(vc[idx] * f16(vn))
// ---------------------------------------------------------------------------
__global__ __launch_bounds__(256, 4) void value_compress(
    const float* __restrict__ v, const float* __restrict__ Rvf,
    const float* __restrict__ vcg, const float* __restrict__ vbg,
    const ushort* __restrict__ Rvb, ushort* __restrict__ VT)
{
    __shared__ ushort u_lds[TBK][136];
    __shared__ unsigned char idx_lds[TBK][128];
    __shared__ float red[4][TBK];
    __shared__ float nrmA[TBK], invA[TBK], hnA[TBK];
    __shared__ float vcl[16], vbl[15];
    __shared__ ushort list1[4][LCW1];

    const int tid = threadIdx.x;
    const int base = blockIdx.x * TBK;
    const int w = tid >> 6, l = tid & 63, lr = l & 15, lh = l >> 4;

    if (tid < 16) vcl[tid] = vcg[tid];
    if (tid < 15) vbl[tid] = vbg[tid];

    const int j0 = tid & 127, th = tid >> 7;
    {
        float kv[16];
        #pragma unroll
        for (int tt = 0; tt < 16; ++tt)
            kv[tt] = v[(size_t)(base + th * 16 + tt) * D + j0];
        float ss[16];
        #pragma unroll
        for (int tt = 0; tt < 16; ++tt) ss[tt] = kv[tt] * kv[tt];
        #pragma unroll
        for (int o = 32; o > 0; o >>= 1) {
            #pragma unroll
            for (int tt = 0; tt < 16; ++tt) ss[tt] += __shfl_xor(ss[tt], o, 64);
        }
        if (l == 0) {
            #pragma unroll
            for (int tt = 0; tt < 16; ++tt) red[w][tt] = ss[tt];
        }
        __syncthreads();
        if (tid < TBK) {
            int t = tid;
            float s2 = red[(t >> 4) * 2][t & 15] + red[(t >> 4) * 2 + 1][t & 15];
            float n = sqrtf(s2);
            nrmA[t] = n;
            invA[t] = 1.0f / (n + 1e-8f);
            hnA[t] = f16r(n);
        }
        __syncthreads();
        #pragma unroll
        for (int tt = 0; tt < 16; ++tt) {
            int t = th * 16 + tt;
            u_lds[t][j0] = f2bf(kv[tt] * invA[t]);
        }
    }
    __syncthreads();

    int c1 = 0;
    float vbr[15];
    #pragma unroll
    for (int i = 0; i < 15; ++i) vbr[i] = vbl[i];

    #pragma unroll
    for (int n = 0; n < 2; ++n) {
        short8v bV[4];
        #pragma unroll
        for (int kk = 0; kk < 4; ++kk)
            bV[kk] = *reinterpret_cast<const short8v*>(
                Rvb + (size_t)(32 * w + 16 * n + lr) * D + kk * 32 + lh * 8);
        #pragma unroll
        for (int a = 0; a < 2; ++a) {
            int tr = 16 * a + lr;
            short8v av[4];
            #pragma unroll
            for (int kk = 0; kk < 4; ++kk)
                av[kk] = *reinterpret_cast<const short8v*>(&u_lds[tr][kk * 32 + lh * 8]);
            f32x4 rt = (f32x4)(0.f);
            #pragma unroll
            for (int kk = 0; kk < 4; ++kk)
                rt = __builtin_amdgcn_mfma_f32_16x16x32_bf16(av[kk], bV[kk], rt, 0, 0, 0);

            #pragma unroll
            for (int r = 0; r < 4; ++r) {
                float x = rt[r];
                int idx = 0;
                float dmin = 1e30f;
                #pragma unroll
                for (int i = 0; i < 15; ++i) {
                    idx += (x > vbr[i]);
                    dmin = fminf(dmin, fabsf(x - vbr[i]));
                }
                int t = 16 * a + 4 * lh + r;
                int jj = 32 * w + 16 * n + lr;
                idx_lds[t][jj] = (unsigned char)idx;
                bool risky = dmin < DROT;
                unsigned long long m = __ballot(risky);
                if (risky) {
                    int pos = c1 + __popcll(m & ((1ULL << l) - 1ULL));
                    if (pos < LCW1) list1[w][pos] = (ushort)((t << 7) | jj);
                }
                c1 += (int)__popcll(m);
            }
        }
    }
    __syncthreads();

    // ---- FB: wave-cooperative coalesced exact recompute ----
    {
        int n1 = min(c1, LCW1);
        const int g = l >> 4, li = l & 15;
        for (int e0 = 0; e0 < n1; e0 += 4) {
            int ee = e0 + g;
            bool act = ee < n1;
            int ent = act ? list1[w][ee] : list1[w][0];
            int t = ent >> 7, jj = ent & 127;
            const float* kr = v + (size_t)(base + t) * D + 8 * li;
            const float* rr = Rvf + (size_t)jj * D + 8 * li;
            float4 ka = *reinterpret_cast<const float4*>(kr);
            float4 kb4 = *reinterpret_cast<const float4*>(kr + 4);
            float4 ra = *reinterpret_cast<const float4*>(rr);
            float4 rb4 = *reinterpret_cast<const float4*>(rr + 4);
            float iv = invA[t];
            float part = (ka.x * iv) * ra.x + (ka.y * iv) * ra.y +
                         (ka.z * iv) * ra.z + (ka.w * iv) * ra.w +
                         (kb4.x * iv) * rb4.x + (kb4.y * iv) * rb4.y +
                         (kb4.z * iv) * rb4.z + (kb4.w * iv) * rb4.w;
            #pragma unroll
            for (int o = 1; o < 16; o <<= 1) part += __shfl_xor(part, o, 64);
            if (act && li == 0) {
                int ni = 0;
                #pragma unroll
                for (int i = 0; i < 15; ++i) ni += (part > vbl[i]);
                idx_lds[t][jj] = (unsigned char)ni;
            }
        }
    }
    __syncthreads();

    // ---- transposed coalesced write ----
    {
        const int c = tid & 127, g = tid >> 7;
        const int hh = base >> 12;
        const int tk = base & 4095;
        ushort tmp[16];
        #pragma unroll
        for (int tt = 0; tt < 16; ++tt) {
            int t = 16 * g + tt;
            tmp[tt] = f2bf(vcl[idx_lds[t][c]] * hnA[t]);
        }
        ushort* dst = VT + ((size_t)hh * D + c) * SEQ_KV + tk + 16 * g;
        uint pk[8];
        #pragma unroll
        for (int i = 0; i < 8; ++i)
            pk[i] = (uint)tmp[2 * i] | ((uint)tmp[2 * i + 1] << 16);
        *reinterpret_cast<uint4*>(dst)     = make_uint4(pk[0], pk[1], pk[2], pk[3]);
        *reinterpret_cast<uint4*>(dst + 8) = make_uint4(pk[4], pk[5], pk[6], pk[7]);
    }
}

// ---------------------------------------------------------------------------
// Q extension: Qx[0:128] = bf16(q@R^T), Qx[128:256] = bf16(q@qjl^T)
// ---------------------------------------------------------------------------
__global__ __launch_bounds__(128) void q_extend(
    const float* __restrict__ q, const float* __restrict__ Rf,
    const float* __restrict__ qjlf, ushort* __restrict__ Qxo)
{
    __shared__ float u[TBQ][132];
    const int j = threadIdx.x;
    const int base = blockIdx.x * TBQ;

    #pragma unroll
    for (int t = 0; t < TBQ; ++t)
        u[t][j] = q[(size_t)(base + t) * D + j];
    __syncthreads();

    float accr[TBQ], accq[TBQ];
    #pragma unroll
    for (int t = 0; t < TBQ; ++t) { accr[t] = 0.f; accq[t] = 0.f; }
    const float* Rr = Rf + (size_t)j * D;
    const float* Qr = qjlf + (size_t)j * D;
    #pragma unroll 2
    for (int d = 0; d < D; d += 4) {
        float4 r4 = *reinterpret_cast<const float4*>(Rr + d);
        float4 q4 = *reinterpret_cast<const float4*>(Qr + d);
        #pragma unroll
        for (int t = 0; t < TBQ; ++t) {
            float4 u4 = *reinterpret_cast<const float4*>(&u[t][d]);
            accr[t] += u4.x * r4.x + u4.y * r4.y + u4.z * r4.z + u4.w * r4.w;
            accq[t] += u4.x * q4.x + u4.y * q4.y + u4.z * q4.z + u4.w * q4.w;
        }
    }
    #pragma unroll
    for (int t = 0; t < TBQ; ++t) {
        Qxo[(size_t)(base + t) * 256 + j]       = f2bf(accr[t]);
        Qxo[(size_t)(base + t) * 256 + 128 + j] = f2bf(accq[t]);
    }
}

// ---------------------------------------------------------------------------
// MFMA flash attention, QT=128 mega-block: 512 threads / 8 waves.
// De-spill design: NO long-lived staging registers (load->LDS immediately,
// tmp regs die before compute); amdgpu_waves_per_eu(4,4) pins the allocator
// at 128 VGPR (2 blocks/CU, the LDS cap) so the ~100-reg live set fits with
// zero scratch spill.
// grid: (HEADS, SEQ_Q/128, KVSPL)
// ---------------------------------------------------------------------------
__global__ __attribute__((amdgpu_flat_work_group_size(512, 512)))
__attribute__((amdgpu_waves_per_eu(4, 4))) void attention(
    const ushort* __restrict__ Qx, const ushort* __restrict__ Kx,
    const ushort* __restrict__ VT, float* __restrict__ Opart,
    float* __restrict__ MLp)
{
    __shared__ __align__(16) unsigned char arena[33792 + 18432 + 19456];
    ushort (*Ks)[264] = (ushort (*)[264])arena;                    // 33792 B
    ushort (*Vs)[72]  = (ushort (*)[72])(arena + 33792);           // 18432 B
    ushort (*Ps)[76]  = (ushort (*)[76])(arena + 33792 + 18432);   // 19456 B (128 rows)
    float (*Of)[130]  = (float (*)[130])arena;                     // 66560 B overlay (epilogue)

    const int tid = threadIdx.x;
    const int h   = blockIdx.x;
    const int q0  = blockIdx.y * 128;
    const int sp  = blockIdx.z;
    const int kvb = sp * KVLEN;
    const int w   = tid >> 6;          // 0..7 waves, 16 q-rows each
    const int l   = tid & 63;
    const int lr  = l & 15;
    const int lh  = l >> 4;
    const float scale = 0.08838834764831845f;  // 1/sqrt(128)

    short8v qa[8];
    {
        const ushort* qrow = Qx + ((size_t)h * SEQ_Q + q0 + w * 16 + lr) * 256 + lh * 8;
        #pragma unroll
        for (int kk = 0; kk < 8; ++kk)
            qa[kk] = __builtin_bit_cast(short8v,
                *reinterpret_cast<const uint4*>(qrow + kk * 32));
    }

    const int krow = tid >> 5, kc16 = tid & 31;   // K: 16 rows per instr
    const int vrow = tid >> 3, vc8  = tid & 7;    // V: 64 rows per instr
    const ushort* Kg = Kx + (size_t)h * SEQ_KV * 256;
    const ushort* Vg = VT + (size_t)h * D * SEQ_KV;

    f32x4 oacc[8];
    #pragma unroll
    for (int dc = 0; dc < 8; ++dc) oacc[dc] = (f32x4)(0.f);
    float mrow[4], lsum[4];
    #pragma unroll
    for (int r = 0; r < 4; ++r) { mrow[r] = -INFINITY; lsum[r] = 0.f; }

    for (int k0 = kvb; k0 < kvb + KVLEN; k0 += 64) {
        __syncthreads();   // all waves done reading previous tile
        {
            // load->store immediately; tmp regs dead before compute phase
            uint4 kt0 = *reinterpret_cast<const uint4*>(
                Kg + (size_t)(k0 + krow) * 256 + kc16 * 8);
            uint4 kt1 = *reinterpret_cast<const uint4*>(
                Kg + (size_t)(k0 + krow + 16) * 256 + kc16 * 8);
            uint4 kt2 = *reinterpret_cast<const uint4*>(
                Kg + (size_t)(k0 + krow + 32) * 256 + kc16 * 8);
            uint4 kt3 = *reinterpret_cast<const uint4*>(
                Kg + (size_t)(k0 + krow + 48) * 256 + kc16 * 8);
            uint4 vt0 = *reinterpret_cast<const uint4*>(
                Vg + (size_t)vrow * SEQ_KV + k0 + vc8 * 8);
            uint4 vt1 = *reinterpret_cast<const uint4*>(
                Vg + (size_t)(vrow + 64) * SEQ_KV + k0 + vc8 * 8);
            *reinterpret_cast<uint4*>(&Ks[krow][kc16 * 8])      = kt0;
            *reinterpret_cast<uint4*>(&Ks[krow + 16][kc16 * 8]) = kt1;
            *reinterpret_cast<uint4*>(&Ks[krow + 32][kc16 * 8]) = kt2;
            *reinterpret_cast<uint4*>(&Ks[krow + 48][kc16 * 8]) = kt3;
            *reinterpret_cast<uint4*>(&Vs[vrow][vc8 * 8])       = vt0;
            *reinterpret_cast<uint4*>(&Vs[vrow + 64][vc8 * 8])  = vt1;
        }
        __syncthreads();

        f32x4 sacc[4];
        #pragma unroll
        for (int kc = 0; kc < 4; ++kc) sacc[kc] = (f32x4)(0.f);
        #pragma unroll
        for (int kk = 0; kk < 8; ++kk) {
            #pragma unroll
            for (int kc = 0; kc < 4; ++kc) {
                short8v b = *reinterpret_cast<const short8v*>(
                    &Ks[kc * 16 + lr][kk * 32 + lh * 8]);
                sacc[kc] = __builtin_amdgcn_mfma_f32_16x16x32_bf16(
                    qa[kk], b, sacc[kc], 0, 0, 0);
            }
        }

        #pragma unroll
        for (int r = 0; r < 4; ++r) {
            float mx = fmaxf(fmaxf(sacc[0][r], sacc[1][r]),
                             fmaxf(sacc[2][r], sacc[3][r]));
            #pragma unroll
            for (int off = 8; off > 0; off >>= 1)
                mx = fmaxf(mx, __shfl_xor(mx, off, 64));
            mx *= scale;
            float mn = fmaxf(mrow[r], mx);
            float alpha = __expf(mrow[r] - mn);
            float pv[4], ps = 0.f;
            #pragma unroll
            for (int kc = 0; kc < 4; ++kc) {
                float p = __expf(sacc[kc][r] * scale - mn);
                pv[kc] = p; ps += p;
            }
            #pragma unroll
            for (int off = 8; off > 0; off >>= 1)
                ps += __shfl_xor(ps, off, 64);
            lsum[r] = lsum[r] * alpha + ps;
            mrow[r] = mn;
            #pragma unroll
            for (int kc = 0; kc < 4; ++kc)
                Ps[w * 16 + lh * 4 + r][kc * 16 + lr] = f2bf(pv[kc]);
            #pragma unroll
            for (int dc = 0; dc < 8; ++dc)
                oacc[dc][r] *= alpha;
        }

        #pragma unroll
        for (int kc2 = 0; kc2 < 2; ++kc2) {
            short8v pa = *reinterpret_cast<const short8v*>(
                &Ps[w * 16 + lr][kc2 * 32 + lh * 8]);
            #pragma unroll
            for (int dc = 0; dc < 8; ++dc) {
                short8v b = *reinterpret_cast<const short8v*>(
                    &Vs[dc * 16 + lr][kc2 * 32 + lh * 8]);
                oacc[dc] = __builtin_amdgcn_mfma_f32_16x16x32_bf16(
                    pa, b, oacc[dc], 0, 0, 0);
            }
        }
    }

    // ---- epilogue: O' -> LDS overlay -> dense global stores ----
    __syncthreads();   // all waves done reading Ks/Vs/Ps
    #pragma unroll
    for (int r = 0; r < 4; ++r) {
        int row = w * 16 + lh * 4 + r;
        #pragma unroll
        for (int dc = 0; dc < 8; ++dc)
            Of[row][dc * 16 + lr] = oacc[dc][r];
        if (lr == 0) {
            int rowg = h * SEQ_Q + q0 + row;
            MLp[((size_t)sp * HS + rowg) * 2 + 0] = mrow[r];
            MLp[((size_t)sp * HS + rowg) * 2 + 1] = lsum[r];
        }
    }
    __syncthreads();
    {
        const int rg = tid >> 5, cl = tid & 31;   // 16 row-groups
        float* obase = Opart + ((size_t)sp * HS + (size_t)h * SEQ_Q + q0) * D;
        #pragma unroll
        for (int it = 0; it < 8; ++it) {
            int row = it * 16 + rg;
            float4 vv = *reinterpret_cast<const float4*>(&Of[row][cl * 4]);
            *reinterpret_cast<float4*>(obase + (size_t)row * D + cl * 4) = vv;
        }
    }
}

// ---------------------------------------------------------------------------
// Combine KVSPL partials + Rv rotation epilogue.
// grid: HS/64, 256 threads. Block handles 64 output rows.
// ---------------------------------------------------------------------------
__global__ __launch_bounds__(256) void combine(
    const float* __restrict__ Opart, const float* __restrict__ MLp,
    const float* __restrict__ Rvf, float* __restrict__ out)
{
    __shared__ float O2[64][133];
    __shared__ float ws_s[KVSPL][64];

    const int tid = threadIdx.x;
    const int rowbase = blockIdx.x * 64;

    if (tid < 64) {
        int row = rowbase + tid;
        float mv[KVSPL], lv[KVSPL];
        #pragma unroll
        for (int s = 0; s < KVSPL; ++s) {
            mv[s] = MLp[((size_t)s * HS + row) * 2 + 0];
            lv[s] = MLp[((size_t)s * HS + row) * 2 + 1];
        }
        float M = mv[0];
        #pragma unroll
        for (int s = 1; s < KVSPL; ++s) M = fmaxf(M, mv[s]);
        float wv[KVSPL], den = 0.f;
        #pragma unroll
        for (int s = 0; s < KVSPL; ++s) {
            wv[s] = __expf(mv[s] - M);
            den += wv[s] * lv[s];
        }
        float inv = 1.0f / den;
        #pragma unroll
        for (int s = 0; s < KVSPL; ++s) ws_s[s][tid] = wv[s] * inv;
    }
    __syncthreads();

    const int rr = tid >> 2, qq = tid & 3;
    {
        int row = rowbase + rr;
        float o[32];
        #pragma unroll
        for (int i = 0; i < 32; ++i) o[i] = 0.f;
        #pragma unroll
        for (int s = 0; s < KVSPL; ++s) {
            const float* pa = Opart + ((size_t)s * HS + row) * D + qq * 32;
            float wgt = ws_s[s][rr];
            #pragma unroll
            for (int c8 = 0; c8 < 8; ++c8) {
                float4 va = *reinterpret_cast<const float4*>(pa + c8 * 4);
                o[c8 * 4 + 0] = fmaf(va.x, wgt, o[c8 * 4 + 0]);
                o[c8 * 4 + 1] = fmaf(va.y, wgt, o[c8 * 4 + 1]);
                o[c8 * 4 + 2] = fmaf(va.z, wgt, o[c8 * 4 + 2]);
                o[c8 * 4 + 3] = fmaf(va.w, wgt, o[c8 * 4 + 3]);
            }
        }
        #pragma unroll
        for (int i = 0; i < 32; ++i) O2[rr][qq * 32 + i] = o[i];
    }
    __syncthreads();

    {
        float acc[32];
        #pragma unroll
        for (int i = 0; i < 32; ++i) acc[i] = 0.f;
        #pragma unroll 2
        for (int jv = 0; jv < 128; ++jv) {
            float o = O2[rr][jv];
            const float* rv = Rvf + (size_t)jv * D + qq * 32;
            #pragma unroll
            for (int c8 = 0; c8 < 8; ++c8) {
                float4 r4 = *reinterpret_cast<const float4*>(rv + c8 * 4);
                acc[c8 * 4 + 0] = fmaf(o, r4.x, acc[c8 * 4 + 0]);
                acc[c8 * 4 + 1] = fmaf(o, r4.y, acc[c8 * 4 + 1]);
                acc[c8 * 4 + 2] = fmaf(o, r4.z, acc[c8 * 4 + 2]);
                acc[c8 * 4 + 3] = fmaf(o, r4.w, acc[c8 * 4 + 3]);
            }
        }
        float* orow = out + (size_t)(rowbase + rr) * D + qq * 32;
        #pragma unroll
        for (int c8 = 0; c8 < 8; ++c8)
            *reinterpret_cast<float4*>(orow + c8 * 4) =
                make_float4(acc[c8 * 4], acc[c8 * 4 + 1], acc[c8 * 4 + 2], acc[c8 * 4 + 3]);
    }
}

extern "C" void kernel_launch(void* const* d_in, const int* in_sizes, int n_in,
                              void* d_out, int out_size, void* d_ws, size_t ws_size,
                              hipStream_t stream)
{
    const float* q    = (const float*)d_in[0];
    const float* k    = (const float*)d_in[1];
    const float* v    = (const float*)d_in[2];
    const float* Rf   = (const float*)d_in[3];
    const float* qjlf = (const float*)d_in[4];
    const float* kc   = (const float*)d_in[5];
    const float* kb   = (const float*)d_in[6];
    const float* Rvf  = (const float*)d_in[7];
    const float* vc   = (const float*)d_in[8];
    const float* vb   = (const float*)d_in[9];
    float* out = (float*)d_out;

    // ws layout (bf16 unless noted)
    ushort* Kx    = (ushort*)d_ws;                       // [H*SKV][256]
    ushort* VT    = Kx + (size_t)HEADS * SEQ_KV * 256;   // [H][128][SKV]
    ushort* Qx    = VT + (size_t)HEADS * D * SEQ_KV;     // [H*SQ][256]
    ushort* Rb    = Qx + (size_t)HEADS * SEQ_Q * 256;    // [128][128]
    ushort* Rvb   = Rb + 16384;
    ushort* qjlb  = Rvb + 16384;
    ushort* MTb   = qjlb + 16384;
    float*  MTf   = (float*)(MTb + 16384);               // [128][128] f32
    float*  qn    = MTf + 16384;                         // [128]
    float*  mn    = qn + 128;                            // [128]
    float*  Opart = mn + 128;                            // [KVSPL][HS][128] f32
    float*  MLp   = Opart + (size_t)KVSPL * HS * D;      // [KVSPL][HS][2] f32

    pack3<<<192, 256, 0, stream>>>(Rf, Rvf, qjlf, Rb, Rvb, qjlb);
    minit<<<128, 128, 0, stream>>>(Rf, qjlf, MTf, MTb, qn, mn);
    key_compress<<<HEADS * SEQ_KV / TBK, 256, 0, stream>>>(
        k, Rf, qjlf, kc, kb, Rb, qjlb, MTb, MTf, qn, mn, Kx);
    value_compress<<<HEADS * SEQ_KV / TBK, 256, 0, stream>>>(
        v, Rvf, vc, vb, Rvb, VT);
    q_extend<<<HEADS * SEQ_Q / TBQ, 128, 0, stream>>>(q, Rf, qjlf, Qx);
    attention<<<dim3(HEADS, SEQ_Q / 128, KVSPL), 512, 0, stream>>>(
        Qx, Kx, VT, Opart, MLp);
    combine<<<HS / 64, 256, 0, stream>>>(Opart, MLp, Rvf, out);
}